// Round 1
// baseline (366.609 us; speedup 1.0000x reference)
//
#include <hip/hip_runtime.h>

#define DEVI __device__ __forceinline__

typedef __attribute__((ext_vector_type(8))) __bf16 bf16x8;
typedef __attribute__((ext_vector_type(4))) float f32x4;

DEVI __bf16 f2bf(float f) {
  unsigned u = __builtin_bit_cast(unsigned, f);
  unsigned r = u + 0x7fffu + ((u >> 16) & 1u);
  unsigned short h = (unsigned short)(r >> 16);
  return __builtin_bit_cast(__bf16, h);
}

DEVI void load_lds16(const void* g, void* l) {
  __builtin_amdgcn_global_load_lds((__attribute__((address_space(1))) const void*)g,
                                   (__attribute__((address_space(3))) void*)l,
                                   16, 0, 0);
}

// ---------------------------------------------------------------------------
// fp32 -> bf16 conversion, 8 elems/thread
// ---------------------------------------------------------------------------
__global__ void convert_bf16(const float* __restrict__ in, __bf16* __restrict__ out, int n8) {
  int stride = gridDim.x * blockDim.x;
  for (int i = blockIdx.x * blockDim.x + threadIdx.x; i < n8; i += stride) {
    float4 a = ((const float4*)in)[i * 2];
    float4 b = ((const float4*)in)[i * 2 + 1];
    bf16x8 o;
    o[0] = f2bf(a.x); o[1] = f2bf(a.y); o[2] = f2bf(a.z); o[3] = f2bf(a.w);
    o[4] = f2bf(b.x); o[5] = f2bf(b.y); o[6] = f2bf(b.z); o[7] = f2bf(b.w);
    ((bf16x8*)out)[i] = o;
  }
}

// ---------------------------------------------------------------------------
// GEMM: out[m,n] = A[m,:] . W[n,:] + bias[n]   (nn.Linear, B^T layout)
// M=8192, N=K=1024. 128x128 tile, BK=32, 4 waves (2x2), 2-phase pipeline.
// MODE 0: out bf16 [BH][S][64]   (Q/K head-split)
// MODE 1: out bf16 [BH][64][S]   (V transposed)
// MODE 2: out fp32 [M][1024]     (final output)
// ---------------------------------------------------------------------------
template<int MODE>
__global__ __launch_bounds__(256, 2) void gemm_bt(
    const __bf16* __restrict__ A, const __bf16* __restrict__ W,
    const float* __restrict__ bias, void* __restrict__ outp)
{
  __shared__ __bf16 As[2][128 * 32];
  __shared__ __bf16 Bs[2][128 * 32];
  const int tid = threadIdx.x;
  const int lane = tid & 63;
  const int ln = lane & 15, g = lane >> 4;
  const int w = tid >> 6;
  const int wr = w >> 1, wc = w & 1;
  const int row0 = blockIdx.x * 128, col0 = blockIdx.y * 128;

  f32x4 acc[4][4] = {};

  auto stage = [&](int buf, int k0) {
#pragma unroll
    for (int i = 0; i < 2; ++i) {
      int c = tid + 256 * i;               // 512 chunks of 16B per tile
      int r = c >> 2, ko = (c & 3) * 8;
      load_lds16(&A[(size_t)(row0 + r) * 1024 + k0 + ko], &As[buf][c * 8]);
      load_lds16(&W[(size_t)(col0 + r) * 1024 + k0 + ko], &Bs[buf][c * 8]);
    }
  };

  stage(0, 0);
#pragma unroll 2
  for (int kt = 0; kt < 32; ++kt) {
    __syncthreads();                        // drains stage of tile kt (vmcnt 0)
    if (kt + 1 < 32) stage((kt + 1) & 1, (kt + 1) * 32);  // prefetch under compute
    const __bf16* as = As[kt & 1];
    const __bf16* bs = Bs[kt & 1];
    bf16x8 aF[4], bF[4];
#pragma unroll
    for (int mi = 0; mi < 4; ++mi)
      aF[mi] = *(const bf16x8*)&as[(wr * 64 + mi * 16 + ln) * 32 + g * 8];
#pragma unroll
    for (int ni = 0; ni < 4; ++ni)
      bF[ni] = *(const bf16x8*)&bs[(wc * 64 + ni * 16 + ln) * 32 + g * 8];
#pragma unroll
    for (int mi = 0; mi < 4; ++mi)
#pragma unroll
      for (int ni = 0; ni < 4; ++ni)
        acc[mi][ni] = __builtin_amdgcn_mfma_f32_16x16x32_bf16(aF[mi], bF[ni], acc[mi][ni], 0, 0, 0);
  }

#pragma unroll
  for (int ni = 0; ni < 4; ++ni) {
    int n = col0 + wc * 64 + ni * 16 + ln;
    float bv = bias[n];
#pragma unroll
    for (int mi = 0; mi < 4; ++mi) {
#pragma unroll
      for (int i = 0; i < 4; ++i) {
        int m = row0 + wr * 64 + mi * 16 + g * 4 + i;   // C-layout: row=(l>>4)*4+i, col=l&15
        float val = acc[mi][ni][i] + bv;
        if (MODE == 2) {
          ((float*)outp)[(size_t)m * 1024 + n] = val;
        } else {
          int b = m >> 11, s = m & 2047, h = n >> 6, d = n & 63;
          size_t idx = (MODE == 0)
            ? ((size_t)((b * 16 + h) * 2048 + s) * 64 + d)
            : ((size_t)((b * 16 + h) * 64 + d) * 2048 + s);
          ((__bf16*)outp)[idx] = f2bf(val);
        }
      }
    }
  }
}

// ---------------------------------------------------------------------------
// Causal flash attention. Grid (S/128, B*H). 4 waves x 32 q-rows.
// Qh,Kh: [BH][S][64] bf16. Vt: [BH][64][S] bf16. Ctx out: [B][S][1024] bf16.
// K/Vt LDS tiles XOR-swizzled (byte ^= (row&7)<<4) via pre-swizzled global src.
// ---------------------------------------------------------------------------
__global__ __launch_bounds__(256, 2) void attn_fwd(
    const __bf16* __restrict__ Qh, const __bf16* __restrict__ Kh,
    const __bf16* __restrict__ Vt, __bf16* __restrict__ Ctx)
{
  __shared__ __bf16 Ks[2][64 * 64];
  __shared__ __bf16 Vs[2][64 * 64];
  __shared__ __bf16 Ps[4][32 * 64];

  const int tid = threadIdx.x;
  const int lane = tid & 63;
  const int ln = lane & 15, g = lane >> 4;
  const int w = tid >> 6;
  const int q0 = blockIdx.x * 128;
  const int bh = blockIdx.y;

  bf16x8 qF[2][2];                         // Q rows in registers
#pragma unroll
  for (int mi = 0; mi < 2; ++mi)
#pragma unroll
    for (int ks = 0; ks < 2; ++ks) {
      int row = q0 + w * 32 + mi * 16 + ln;
      qF[mi][ks] = *(const bf16x8*)&Qh[((size_t)bh * 2048 + row) * 64 + ks * 32 + g * 8];
    }

  f32x4 oF[2][4] = {};
  float mrun[2][4], lrun[2][4];
#pragma unroll
  for (int mi = 0; mi < 2; ++mi)
#pragma unroll
    for (int i = 0; i < 4; ++i) { mrun[mi][i] = -3e38f; lrun[mi][i] = 0.f; }

  const int nt = q0 / 64 + 2;              // causal: only tiles up to the diagonal

  auto stageKV = [&](int buf, int t) {
    int kv0 = t * 64;
#pragma unroll
    for (int i = 0; i < 2; ++i) {
      int c = tid + 256 * i;               // 512 chunks of 16B
      int r = c >> 3, sl = c & 7;
      int so = 8 * (sl ^ (r & 7));         // inverse-swizzled source offset
      load_lds16(&Kh[((size_t)bh * 2048 + kv0 + r) * 64 + so], &Ks[buf][c * 8]);
      load_lds16(&Vt[((size_t)bh * 64 + r) * 2048 + kv0 + so], &Vs[buf][c * 8]);
    }
  };

  stageKV(0, 0);
#pragma unroll 2
  for (int t = 0; t < nt; ++t) {
    __syncthreads();
    if (t + 1 < nt) stageKV((t + 1) & 1, t + 1);
    const __bf16* ksm = Ks[t & 1];
    const __bf16* vsm = Vs[t & 1];
    const int kv0 = t * 64;

    // ---- S = Q K^T ----
    f32x4 sF[2][4] = {};
#pragma unroll
    for (int ksb = 0; ksb < 2; ++ksb) {
      bf16x8 bF[4];
#pragma unroll
      for (int ni = 0; ni < 4; ++ni) {
        int r = ni * 16 + ln;
        bF[ni] = *(const bf16x8*)&ksm[r * 64 + ((ksb * 32 + g * 8) ^ ((r & 7) * 8))];
      }
#pragma unroll
      for (int mi = 0; mi < 2; ++mi)
#pragma unroll
        for (int ni = 0; ni < 4; ++ni)
          sF[mi][ni] = __builtin_amdgcn_mfma_f32_16x16x32_bf16(qF[mi][ksb], bF[ni], sF[mi][ni], 0, 0, 0);
    }

    // ---- scale + causal mask + online softmax (wave-parallel) ----
#pragma unroll
    for (int mi = 0; mi < 2; ++mi) {
      float tmax[4];
#pragma unroll
      for (int i = 0; i < 4; ++i) {
        int qrow = q0 + w * 32 + mi * 16 + g * 4 + i;
        float mx = -3e38f;
#pragma unroll
        for (int ni = 0; ni < 4; ++ni) {
          int kvg = kv0 + ni * 16 + ln;
          float s = sF[mi][ni][i] * 0.125f;          // 1/sqrt(64)
          s = (kvg <= qrow) ? s : -3e38f;
          sF[mi][ni][i] = s;
          mx = fmaxf(mx, s);
        }
        tmax[i] = mx;
      }
#pragma unroll
      for (int msk = 1; msk < 16; msk <<= 1)
#pragma unroll
        for (int i = 0; i < 4; ++i)
          tmax[i] = fmaxf(tmax[i], __shfl_xor(tmax[i], msk));
#pragma unroll
      for (int i = 0; i < 4; ++i) {
        float mnew = fmaxf(mrun[mi][i], tmax[i]);
        float fac = exp2f((mrun[mi][i] - mnew) * 1.44269504f);
        mrun[mi][i] = mnew;
        lrun[mi][i] *= fac;
#pragma unroll
        for (int di = 0; di < 4; ++di) oF[mi][di][i] *= fac;
        float psum = 0.f;
#pragma unroll
        for (int ni = 0; ni < 4; ++ni) {
          float p = exp2f((sF[mi][ni][i] - mnew) * 1.44269504f);
          sF[mi][ni][i] = p;
          psum += p;
        }
        lrun[mi][i] += psum;                // lane-partial; reduced once at end
      }
    }

    // ---- P (score layout) -> per-wave LDS -> A-operand layout ----
    __bf16* ps = Ps[w];
#pragma unroll
    for (int mi = 0; mi < 2; ++mi)
#pragma unroll
      for (int ni = 0; ni < 4; ++ni)
#pragma unroll
        for (int i = 0; i < 4; ++i) {
          int ql = mi * 16 + g * 4 + i;
          int el = (ni * 16 + ln) ^ ((ql & 7) * 8);
          ps[ql * 64 + el] = f2bf(sF[mi][ni][i]);
        }

    // ---- O += P V ----
#pragma unroll
    for (int ksb = 0; ksb < 2; ++ksb) {
      bf16x8 aP[2], bV[4];
#pragma unroll
      for (int mi = 0; mi < 2; ++mi) {
        int r = mi * 16 + ln;
        aP[mi] = *(const bf16x8*)&ps[r * 64 + ((ksb * 32 + g * 8) ^ ((r & 7) * 8))];
      }
#pragma unroll
      for (int di = 0; di < 4; ++di) {
        int r = di * 16 + ln;
        bV[di] = *(const bf16x8*)&vsm[r * 64 + ((ksb * 32 + g * 8) ^ ((r & 7) * 8))];
      }
#pragma unroll
      for (int mi = 0; mi < 2; ++mi)
#pragma unroll
        for (int di = 0; di < 4; ++di)
          oF[mi][di] = __builtin_amdgcn_mfma_f32_16x16x32_bf16(aP[mi], bV[di], oF[mi][di], 0, 0, 0);
    }
  }

  // ---- finalize: reduce l, divide, write ctx [B][S][1024] ----
  const int b = bh >> 4, h = bh & 15;
#pragma unroll
  for (int mi = 0; mi < 2; ++mi) {
#pragma unroll
    for (int msk = 1; msk < 16; msk <<= 1)
#pragma unroll
      for (int i = 0; i < 4; ++i)
        lrun[mi][i] += __shfl_xor(lrun[mi][i], msk);
#pragma unroll
    for (int i = 0; i < 4; ++i) {
      float inv = 1.0f / lrun[mi][i];
      int qrow = q0 + w * 32 + mi * 16 + g * 4 + i;
#pragma unroll
      for (int di = 0; di < 4; ++di) {
        int d = di * 16 + ln;
        Ctx[((size_t)(b * 2048 + qrow)) * 1024 + h * 64 + d] = f2bf(oF[mi][di][i] * inv);
      }
    }
  }
}

// ---------------------------------------------------------------------------
extern "C" void kernel_launch(void* const* d_in, const int* in_sizes, int n_in,
                              void* d_out, int out_size, void* d_ws, size_t ws_size,
                              hipStream_t stream) {
  const float* q  = (const float*)d_in[0];
  const float* k  = (const float*)d_in[1];
  const float* v  = (const float*)d_in[2];
  const float* wq = (const float*)d_in[3];
  const float* bq = (const float*)d_in[4];
  const float* wk = (const float*)d_in[5];
  const float* bk = (const float*)d_in[6];
  const float* wv = (const float*)d_in[7];
  const float* bv = (const float*)d_in[8];
  const float* wo = (const float*)d_in[9];
  const float* bo = (const float*)d_in[10];
  float* out = (float*)d_out;
  char* ws = (char*)d_ws;

  const size_t MB = 1024 * 1024;
  __bf16* Wqb  = (__bf16*)(ws + 0 * MB);
  __bf16* Wkb  = (__bf16*)(ws + 2 * MB);
  __bf16* Wvb  = (__bf16*)(ws + 4 * MB);
  __bf16* Wob  = (__bf16*)(ws + 6 * MB);
  __bf16* Abuf = (__bf16*)(ws + 8 * MB);   // 16 MB, reused for q/k/v then ctx
  __bf16* Qh   = (__bf16*)(ws + 24 * MB);
  __bf16* Kh   = (__bf16*)(ws + 40 * MB);
  __bf16* Vt   = (__bf16*)(ws + 56 * MB);  // ends at 72 MB
  __bf16* Ctx  = Abuf;

  const int W8 = 1024 * 1024 / 8;
  const int X8 = 8192 * 1024 / 8;
  auto cgrid = [](int n8) { int nb = (n8 + 255) / 256; return dim3((unsigned)(nb < 2048 ? nb : 2048)); };

  convert_bf16<<<cgrid(W8), 256, 0, stream>>>(wq, Wqb, W8);
  convert_bf16<<<cgrid(W8), 256, 0, stream>>>(wk, Wkb, W8);
  convert_bf16<<<cgrid(W8), 256, 0, stream>>>(wv, Wvb, W8);
  convert_bf16<<<cgrid(W8), 256, 0, stream>>>(wo, Wob, W8);

  dim3 ggrid(64, 8);
  convert_bf16<<<cgrid(X8), 256, 0, stream>>>(q, Abuf, X8);
  gemm_bt<0><<<ggrid, 256, 0, stream>>>(Abuf, Wqb, bq, Qh);
  convert_bf16<<<cgrid(X8), 256, 0, stream>>>(k, Abuf, X8);
  gemm_bt<0><<<ggrid, 256, 0, stream>>>(Abuf, Wkb, bk, Kh);
  convert_bf16<<<cgrid(X8), 256, 0, stream>>>(v, Abuf, X8);
  gemm_bt<1><<<ggrid, 256, 0, stream>>>(Abuf, Wvb, bv, Vt);

  attn_fwd<<<dim3(16, 64), 256, 0, stream>>>(Qh, Kh, Vt, Ctx);
  gemm_bt<2><<<ggrid, 256, 0, stream>>>(Ctx, Wob, bo, out);
}

// Round 2
// 234.969 us; speedup vs baseline: 1.5602x; 1.5602x over previous
//
#include <hip/hip_runtime.h>

#define DEVI __device__ __forceinline__

typedef __attribute__((ext_vector_type(8))) __bf16 bf16x8;
typedef __attribute__((ext_vector_type(4))) float f32x4;

DEVI __bf16 f2bf(float f) {
  unsigned u = __builtin_bit_cast(unsigned, f);
  unsigned r = u + 0x7fffu + ((u >> 16) & 1u);
  unsigned short h = (unsigned short)(r >> 16);
  return __builtin_bit_cast(__bf16, h);
}

DEVI unsigned cvt_pk_bf16(float lo, float hi) {
  unsigned r;
  asm("v_cvt_pk_bf16_f32 %0, %1, %2" : "=v"(r) : "v"(lo), "v"(hi));
  return r;
}

DEVI void load_lds16(const void* g, void* l) {
  __builtin_amdgcn_global_load_lds((__attribute__((address_space(1))) const void*)g,
                                   (__attribute__((address_space(3))) void*)l,
                                   16, 0, 0);
}

// ---------------------------------------------------------------------------
// fp32 -> bf16 conversion, 8 elems/thread
// ---------------------------------------------------------------------------
__global__ void convert_bf16(const float* __restrict__ in, __bf16* __restrict__ out, int n8) {
  int stride = gridDim.x * blockDim.x;
  for (int i = blockIdx.x * blockDim.x + threadIdx.x; i < n8; i += stride) {
    float4 a = ((const float4*)in)[i * 2];
    float4 b = ((const float4*)in)[i * 2 + 1];
    bf16x8 o;
    o[0] = f2bf(a.x); o[1] = f2bf(a.y); o[2] = f2bf(a.z); o[3] = f2bf(a.w);
    o[4] = f2bf(b.x); o[5] = f2bf(b.y); o[6] = f2bf(b.z); o[7] = f2bf(b.w);
    ((bf16x8*)out)[i] = o;
  }
}

// ---------------------------------------------------------------------------
// GEMM: out[m,n] = A[m,:] . W[n,:] + bias[n]   (nn.Linear, B^T layout)
// M=8192, N=K=1024. 128x128 tile, BK=32, 4 waves (2x2), 2-phase pipeline.
// MODE 0: out bf16 [BH][S][64]   (Q/K head-split)
// MODE 1: out bf16 [BH][64][S]   (V transposed)
// MODE 2: out fp32 [M][1024]     (final output)
// ---------------------------------------------------------------------------
template<int MODE>
__global__ __launch_bounds__(256, 2) void gemm_bt(
    const __bf16* __restrict__ A, const __bf16* __restrict__ W,
    const float* __restrict__ bias, void* __restrict__ outp)
{
  __shared__ __bf16 As[2][128 * 32];
  __shared__ __bf16 Bs[2][128 * 32];
  const int tid = threadIdx.x;
  const int lane = tid & 63;
  const int ln = lane & 15, g = lane >> 4;
  const int w = tid >> 6;
  const int wr = w >> 1, wc = w & 1;
  const int row0 = blockIdx.x * 128, col0 = blockIdx.y * 128;

  f32x4 acc[4][4] = {};

  auto stage = [&](int buf, int k0) {
#pragma unroll
    for (int i = 0; i < 2; ++i) {
      int c = tid + 256 * i;               // 512 chunks of 16B per tile
      int r = c >> 2, ko = (c & 3) * 8;
      load_lds16(&A[(size_t)(row0 + r) * 1024 + k0 + ko], &As[buf][c * 8]);
      load_lds16(&W[(size_t)(col0 + r) * 1024 + k0 + ko], &Bs[buf][c * 8]);
    }
  };

  stage(0, 0);
#pragma unroll 2
  for (int kt = 0; kt < 32; ++kt) {
    __syncthreads();                        // drains stage of tile kt (vmcnt 0)
    if (kt + 1 < 32) stage((kt + 1) & 1, (kt + 1) * 32);  // prefetch under compute
    const __bf16* as = As[kt & 1];
    const __bf16* bs = Bs[kt & 1];
    bf16x8 aF[4], bF[4];
#pragma unroll
    for (int mi = 0; mi < 4; ++mi)
      aF[mi] = *(const bf16x8*)&as[(wr * 64 + mi * 16 + ln) * 32 + g * 8];
#pragma unroll
    for (int ni = 0; ni < 4; ++ni)
      bF[ni] = *(const bf16x8*)&bs[(wc * 64 + ni * 16 + ln) * 32 + g * 8];
#pragma unroll
    for (int mi = 0; mi < 4; ++mi)
#pragma unroll
      for (int ni = 0; ni < 4; ++ni)
        acc[mi][ni] = __builtin_amdgcn_mfma_f32_16x16x32_bf16(aF[mi], bF[ni], acc[mi][ni], 0, 0, 0);
  }

#pragma unroll
  for (int ni = 0; ni < 4; ++ni) {
    int n = col0 + wc * 64 + ni * 16 + ln;
    float bv = bias[n];
#pragma unroll
    for (int mi = 0; mi < 4; ++mi) {
#pragma unroll
      for (int i = 0; i < 4; ++i) {
        int m = row0 + wr * 64 + mi * 16 + g * 4 + i;   // C-layout: row=(l>>4)*4+i, col=l&15
        float val = acc[mi][ni][i] + bv;
        if (MODE == 2) {
          ((float*)outp)[(size_t)m * 1024 + n] = val;
        } else {
          int b = m >> 11, s = m & 2047, h = n >> 6, d = n & 63;
          size_t idx = (MODE == 0)
            ? ((size_t)((b * 16 + h) * 2048 + s) * 64 + d)
            : ((size_t)((b * 16 + h) * 64 + d) * 2048 + s);
          ((__bf16*)outp)[idx] = f2bf(val);
        }
      }
    }
  }
}

// ---------------------------------------------------------------------------
// Causal flash attention, swapped-operand form (S^T = K Q^T, O^T = V^T P).
// Grid (B*H, S/128), blockIdx.y REVERSED so heavy diagonal blocks launch first.
// 4 waves x 32 q-rows. q-row is lane-local (q = lane&15) in both S^T and O^T,
// so softmax max-reduce is 15 in-lane fmax + 2 shfl, and fac/l rescale of the
// accumulator needs NO cross-lane traffic.
// Qh,Kh: [BH][S][64] bf16. Vt: [BH][64][S] bf16. Ctx out: [B][S][1024] bf16.
// K/Vt LDS tiles XOR-swizzled (byte ^= (row&7)<<4) via pre-swizzled global src.
// P: per-wave LDS [16 q][64 kv], packed b64 writes (cvt_pk), swizzled b128 reads.
// ---------------------------------------------------------------------------
__global__ __launch_bounds__(256, 3) void attn_fwd(
    const __bf16* __restrict__ Qh, const __bf16* __restrict__ Kh,
    const __bf16* __restrict__ Vt, __bf16* __restrict__ Ctx)
{
  __shared__ __bf16 Ks[2][64 * 64];
  __shared__ __bf16 Vs[2][64 * 64];
  __shared__ __align__(16) char Pbuf[4][2][2048];   // [wave][qt][16 rows x 128B]

  const int tid = threadIdx.x;
  const int lane = tid & 63;
  const int ln = lane & 15, g = lane >> 4;
  const int w = tid >> 6;
  const int bh = blockIdx.x;
  const int q0 = (int)(gridDim.y - 1 - blockIdx.y) * 128;  // heavy tiles first
  const int qw = q0 + w * 32;
  const float CE = 0.18033688f;                      // (1/sqrt(64)) * log2(e)

  bf16x8 qF[2][2];                                   // Q rows, B-operand: n=q=ln
#pragma unroll
  for (int qt = 0; qt < 2; ++qt)
#pragma unroll
    for (int ksb = 0; ksb < 2; ++ksb)
      qF[qt][ksb] = *(const bf16x8*)&Qh[((size_t)bh * 2048 + qw + qt * 16 + ln) * 64 + ksb * 32 + g * 8];

  f32x4 oT[2][4] = {};                               // O^T: d = 16*di+4g+i, q = ln
  float mrun[2] = {-3e38f, -3e38f}, lrun[2] = {0.f, 0.f};

  const int nt = q0 / 64 + 2;

  auto stageKV = [&](int buf, int t) {
    int kv0 = t * 64;
#pragma unroll
    for (int i = 0; i < 2; ++i) {
      int c = tid + 256 * i;                         // 512 chunks of 16B
      int r = c >> 3, sl = c & 7;
      int so = 8 * (sl ^ (r & 7));                   // inverse-swizzled source offset
      load_lds16(&Kh[((size_t)bh * 2048 + kv0 + r) * 64 + so], &Ks[buf][c * 8]);
      load_lds16(&Vt[((size_t)bh * 64 + r) * 2048 + kv0 + so], &Vs[buf][c * 8]);
    }
  };

  stageKV(0, 0);
  for (int t = 0; t < nt; ++t) {
    __syncthreads();
    if (t + 1 < nt) stageKV((t + 1) & 1, t + 1);     // cooperative: before any skip!
    const int kv0 = t * 64;
    if (kv0 > qw + 31) continue;                     // wave fully above diagonal
    const __bf16* ksm = Ks[t & 1];
    const __bf16* vsm = Vs[t & 1];
    const bool need_mask = (kv0 + 63 > qw);

    // ---- S^T = K Q^T : C[m=kv][n=q], kv = kv0+16ni+4g+i, q = qw+16qt+ln ----
    f32x4 sT[2][4] = {};
#pragma unroll
    for (int ksb = 0; ksb < 2; ++ksb) {
      bf16x8 aK[4];
#pragma unroll
      for (int ni = 0; ni < 4; ++ni) {
        int r = ni * 16 + ln;
        aK[ni] = *(const bf16x8*)&ksm[r * 64 + ((ksb * 32 + g * 8) ^ ((r & 7) * 8))];
      }
#pragma unroll
      for (int qt = 0; qt < 2; ++qt)
#pragma unroll
        for (int ni = 0; ni < 4; ++ni)
          sT[qt][ni] = __builtin_amdgcn_mfma_f32_16x16x32_bf16(aK[ni], qF[qt][ksb], sT[qt][ni], 0, 0, 0);
    }

    // ---- per-qt online softmax: q-row = ln is lane-local ----
#pragma unroll
    for (int qt = 0; qt < 2; ++qt) {
      const int qglob = qw + qt * 16 + ln;
      if (need_mask) {
#pragma unroll
        for (int ni = 0; ni < 4; ++ni)
#pragma unroll
          for (int i = 0; i < 4; ++i) {
            int kvg = kv0 + ni * 16 + 4 * g + i;
            sT[qt][ni][i] = (kvg <= qglob) ? sT[qt][ni][i] : -3e38f;
          }
      }
      f32x4 vm0, vm1;
#pragma unroll
      for (int i = 0; i < 4; ++i) {
        vm0[i] = fmaxf(sT[qt][0][i], sT[qt][1][i]);
        vm1[i] = fmaxf(sT[qt][2][i], sT[qt][3][i]);
      }
      float mx = fmaxf(fmaxf(fmaxf(vm0[0], vm0[1]), fmaxf(vm0[2], vm0[3])),
                       fmaxf(fmaxf(vm1[0], vm1[1]), fmaxf(vm1[2], vm1[3])));
      mx = fmaxf(mx, __shfl_xor(mx, 16));
      mx = fmaxf(mx, __shfl_xor(mx, 32));
      float mnew = fmaxf(mrun[qt], mx);
      float fac = exp2f((mrun[qt] - mnew) * CE);
      mrun[qt] = mnew;
      float psum = 0.f;
      char* pw = Pbuf[w][qt];
#pragma unroll
      for (int ni = 0; ni < 4; ++ni) {
        float p0 = exp2f((sT[qt][ni][0] - mnew) * CE);
        float p1 = exp2f((sT[qt][ni][1] - mnew) * CE);
        float p2 = exp2f((sT[qt][ni][2] - mnew) * CE);
        float p3 = exp2f((sT[qt][ni][3] - mnew) * CE);
        psum += (p0 + p1) + (p2 + p3);
        unsigned d0 = cvt_pk_bf16(p0, p1);
        unsigned d1 = cvt_pk_bf16(p2, p3);
        *(uint2*)(pw + ln * 128 + ((32 * ni + 8 * g) ^ ((ln & 7) << 4))) = make_uint2(d0, d1);
      }
      lrun[qt] = lrun[qt] * fac + psum;
#pragma unroll
      for (int di = 0; di < 4; ++di)
#pragma unroll
        for (int i = 0; i < 4; ++i)
          oT[qt][di][i] *= fac;
    }

    asm volatile("" ::: "memory");                   // order P writes before reads

    // ---- O^T += V^T P : A = Vt rows (m=d), B = P[q][kv] (n=q=ln) ----
#pragma unroll
    for (int ksb = 0; ksb < 2; ++ksb) {
      bf16x8 aV[4], bP[2];
#pragma unroll
      for (int di = 0; di < 4; ++di) {
        int r = di * 16 + ln;
        aV[di] = *(const bf16x8*)&vsm[r * 64 + ((ksb * 32 + g * 8) ^ ((r & 7) * 8))];
      }
#pragma unroll
      for (int qt = 0; qt < 2; ++qt)
        bP[qt] = *(const bf16x8*)(Pbuf[w][qt] + ln * 128 + ((64 * ksb + 16 * g) ^ ((ln & 7) << 4)));
#pragma unroll
      for (int qt = 0; qt < 2; ++qt)
#pragma unroll
        for (int di = 0; di < 4; ++di)
          oT[qt][di] = __builtin_amdgcn_mfma_f32_16x16x32_bf16(aV[di], bP[qt], oT[qt][di], 0, 0, 0);
    }
  }

  // ---- finalize: l is in-lane (q=ln); pack 4 consecutive d per store ----
  const int b = bh >> 4, h = bh & 15;
#pragma unroll
  for (int qt = 0; qt < 2; ++qt) {
    float lr = lrun[qt];
    lr += __shfl_xor(lr, 16);
    lr += __shfl_xor(lr, 32);
    float inv = 1.0f / lr;
    int qrow = qw + qt * 16 + ln;
#pragma unroll
    for (int di = 0; di < 4; ++di) {
      unsigned o01 = cvt_pk_bf16(oT[qt][di][0] * inv, oT[qt][di][1] * inv);
      unsigned o23 = cvt_pk_bf16(oT[qt][di][2] * inv, oT[qt][di][3] * inv);
      size_t idx = ((size_t)(b * 2048 + qrow)) * 1024 + h * 64 + di * 16 + 4 * g;
      *(uint2*)&Ctx[idx] = make_uint2(o01, o23);
    }
  }
}

// ---------------------------------------------------------------------------
extern "C" void kernel_launch(void* const* d_in, const int* in_sizes, int n_in,
                              void* d_out, int out_size, void* d_ws, size_t ws_size,
                              hipStream_t stream) {
  const float* q  = (const float*)d_in[0];
  const float* k  = (const float*)d_in[1];
  const float* v  = (const float*)d_in[2];
  const float* wq = (const float*)d_in[3];
  const float* bq = (const float*)d_in[4];
  const float* wk = (const float*)d_in[5];
  const float* bk = (const float*)d_in[6];
  const float* wv = (const float*)d_in[7];
  const float* bv = (const float*)d_in[8];
  const float* wo = (const float*)d_in[9];
  const float* bo = (const float*)d_in[10];
  float* out = (float*)d_out;
  char* ws = (char*)d_ws;

  const size_t MB = 1024 * 1024;
  __bf16* Wqb  = (__bf16*)(ws + 0 * MB);
  __bf16* Wkb  = (__bf16*)(ws + 2 * MB);
  __bf16* Wvb  = (__bf16*)(ws + 4 * MB);
  __bf16* Wob  = (__bf16*)(ws + 6 * MB);
  __bf16* Abuf = (__bf16*)(ws + 8 * MB);   // 16 MB, reused for q/k/v then ctx
  __bf16* Qh   = (__bf16*)(ws + 24 * MB);
  __bf16* Kh   = (__bf16*)(ws + 40 * MB);
  __bf16* Vt   = (__bf16*)(ws + 56 * MB);  // ends at 72 MB
  __bf16* Ctx  = Abuf;

  const int W8 = 1024 * 1024 / 8;
  const int X8 = 8192 * 1024 / 8;
  auto cgrid = [](int n8) { int nb = (n8 + 255) / 256; return dim3((unsigned)(nb < 2048 ? nb : 2048)); };

  convert_bf16<<<cgrid(W8), 256, 0, stream>>>(wq, Wqb, W8);
  convert_bf16<<<cgrid(W8), 256, 0, stream>>>(wk, Wkb, W8);
  convert_bf16<<<cgrid(W8), 256, 0, stream>>>(wv, Wvb, W8);
  convert_bf16<<<cgrid(W8), 256, 0, stream>>>(wo, Wob, W8);

  dim3 ggrid(64, 8);
  convert_bf16<<<cgrid(X8), 256, 0, stream>>>(q, Abuf, X8);
  gemm_bt<0><<<ggrid, 256, 0, stream>>>(Abuf, Wqb, bq, Qh);
  convert_bf16<<<cgrid(X8), 256, 0, stream>>>(k, Abuf, X8);
  gemm_bt<0><<<ggrid, 256, 0, stream>>>(Abuf, Wkb, bk, Kh);
  convert_bf16<<<cgrid(X8), 256, 0, stream>>>(v, Abuf, X8);
  gemm_bt<1><<<ggrid, 256, 0, stream>>>(Abuf, Wvb, bv, Vt);

  attn_fwd<<<dim3(64, 16), 256, 0, stream>>>(Qh, Kh, Vt, Ctx);
  gemm_bt<2><<<ggrid, 256, 0, stream>>>(Ctx, Wob, bo, out);
}